// Round 1
// baseline (126.787 us; speedup 1.0000x reference)
//
#include <hip/hip_runtime.h>
#include <stdint.h>

#define B_ROWS 4096
#define D_DIM 128
#define NROW 8192          // 2B
#define TEMP_INV 10.0f     // 1/0.1
#define L2EPS 1e-12f
#define LDS_STRIDE 136     // 128 + 8 bf16 pad -> 272 B rows, 16B-aligned chunks

typedef __attribute__((ext_vector_type(8))) short short8;
typedef __attribute__((ext_vector_type(4))) float f32x4;

static __device__ inline ushort f2bf(float f) {
    union { float f; uint32_t u; } v; v.f = f;
    uint32_t u = v.u;
    uint32_t r = (u + 0x7fffu + ((u >> 16) & 1u)) >> 16;   // RNE
    return (ushort)r;
}

// Kernel 1: L2-normalize rows of [x_i; x_j] -> bf16 Z, and zero denom/pos.
// 1 wave per row, lane handles elements 2l, 2l+1.
__global__ __launch_bounds__(256) void k_normalize(
        const float* __restrict__ xi, const float* __restrict__ xj,
        ushort* __restrict__ z, float* __restrict__ denom,
        float* __restrict__ pos_acc) {
    const int wave = threadIdx.x >> 6;
    const int lane = threadIdx.x & 63;
    const int row = blockIdx.x * 4 + wave;
    const float* src = (row < B_ROWS) ? (xi + (size_t)row * D_DIM)
                                      : (xj + (size_t)(row - B_ROWS) * D_DIM);
    float2 v = *(const float2*)(src + lane * 2);
    float ss = v.x * v.x + v.y * v.y;
#pragma unroll
    for (int m = 32; m >= 1; m >>= 1) ss += __shfl_xor(ss, m, 64);
    const float scale = 1.0f / fmaxf(sqrtf(ss), L2EPS);
    ushort2 o;
    o.x = f2bf(v.x * scale);
    o.y = f2bf(v.y * scale);
    *(ushort2*)(z + (size_t)row * D_DIM + lane * 2) = o;

    if (threadIdx.x < 4) denom[blockIdx.x * 4 + threadIdx.x] = 0.0f;
    if (blockIdx.x == 0 && threadIdx.x == 4) pos_acc[0] = 0.0f;
}

// Kernel 2: fused sim = Z Z^T with row-sum of exp(sim/T) (diag excluded) and
// positive extraction. Block tile: 64 rows x 128 cols, K=128 (no K loop).
// 4 waves; wave w owns rows [w*16, w*16+16) x all 128 cols.
__global__ __launch_bounds__(256) void k_gemm(
        const ushort* __restrict__ z, float* __restrict__ denom,
        float* __restrict__ pos_acc) {
    __shared__ __align__(16) ushort lds_a[64 * LDS_STRIDE];
    __shared__ __align__(16) ushort lds_b[128 * LDS_STRIDE];
    const int ct = blockIdx.x;          // 0..63  (col tiles of 128)
    const int rt = blockIdx.y;          // 0..127 (row tiles of 64)
    const int rowbase = rt * 64, colbase = ct * 128;
    const int t = threadIdx.x;

    // Stage tiles: global rows are 16 chunks of 8 bf16 (uint4 each).
    const uint4* ga = (const uint4*)(z + (size_t)rowbase * D_DIM);
    const uint4* gb = (const uint4*)(z + (size_t)colbase * D_DIM);
#pragma unroll
    for (int i = 0; i < 4; i++) {       // A: 64 rows * 16 chunks = 1024
        int idx = i * 256 + t;
        *(uint4*)&lds_a[(idx >> 4) * LDS_STRIDE + (idx & 15) * 8] = ga[idx];
    }
#pragma unroll
    for (int i = 0; i < 8; i++) {       // B: 128 rows * 16 chunks = 2048
        int idx = i * 256 + t;
        *(uint4*)&lds_b[(idx >> 4) * LDS_STRIDE + (idx & 15) * 8] = gb[idx];
    }
    __syncthreads();

    const int wave = t >> 6, lane = t & 63;
    const int quad = lane >> 4, lc = lane & 15;
    const int wrow = wave * 16;

    // A fragments: A[m=lc][k = kk*32 + quad*8 + j], j=0..7 contiguous -> b128.
    short8 afr[4];
#pragma unroll
    for (int kk = 0; kk < 4; kk++)
        afr[kk] = *(const short8*)&lds_a[(wrow + lc) * LDS_STRIDE + kk * 32 + quad * 8];

    float rowsum[4] = {0.f, 0.f, 0.f, 0.f};
    float posp = 0.f;
    const int rbase = rowbase + wrow + quad * 4;   // C layout: row = quad*4+reg

#pragma unroll
    for (int cs = 0; cs < 8; cs++) {
        short8 bfr[4];
#pragma unroll
        for (int kk = 0; kk < 4; kk++)
            bfr[kk] = *(const short8*)&lds_b[(cs * 16 + lc) * LDS_STRIDE + kk * 32 + quad * 8];
        f32x4 acc = {0.f, 0.f, 0.f, 0.f};
#pragma unroll
        for (int kk = 0; kk < 4; kk++)
            acc = __builtin_amdgcn_mfma_f32_16x16x32_bf16(afr[kk], bfr[kk], acc, 0, 0, 0);
        const int cg = colbase + cs * 16 + lc;     // C layout: col = lane&15
#pragma unroll
        for (int reg = 0; reg < 4; reg++) {
            const int rg = rbase + reg;
            const float s = acc[reg];
            rowsum[reg] += (rg == cg) ? 0.0f : __expf(s * TEMP_INV);
            if (cg == (rg ^ B_ROWS)) posp += s;    // (r+B) mod 2B == r^B
        }
    }

    // Reduce each row's partial over the 16 column-lanes (low 4 lane bits).
#pragma unroll
    for (int reg = 0; reg < 4; reg++) {
        float v = rowsum[reg];
        v += __shfl_xor(v, 1, 64);
        v += __shfl_xor(v, 2, 64);
        v += __shfl_xor(v, 4, 64);
        v += __shfl_xor(v, 8, 64);
        if (lc == 0) atomicAdd(&denom[rbase + reg], v);
    }

    // Positives live only in blocks where colbase range contains rowbase^4096.
    if (((rt ^ 64) >> 1) == ct) {
#pragma unroll
        for (int m = 32; m >= 1; m >>= 1) posp += __shfl_xor(posp, m, 64);
        if (lane == 0) atomicAdd(pos_acc, posp);
    }
}

// Kernel 3: loss = (sum_r log(denom[r]) - pos_sum/T) / (2B)
__global__ __launch_bounds__(256) void k_final(
        const float* __restrict__ denom, const float* __restrict__ pos_acc,
        float* __restrict__ out) {
    __shared__ float red[4];
    const int t = threadIdx.x;
    float s = 0.f;
    for (int r = t; r < NROW; r += 256) s += __logf(denom[r]);
#pragma unroll
    for (int m = 32; m >= 1; m >>= 1) s += __shfl_xor(s, m, 64);
    if ((t & 63) == 0) red[t >> 6] = s;
    __syncthreads();
    if (t == 0) {
        float total = red[0] + red[1] + red[2] + red[3];
        out[0] = (total - pos_acc[0] * TEMP_INV) / (float)NROW;
    }
}

extern "C" void kernel_launch(void* const* d_in, const int* in_sizes, int n_in,
                              void* d_out, int out_size, void* d_ws, size_t ws_size,
                              hipStream_t stream) {
    const float* xi = (const float*)d_in[0];
    const float* xj = (const float*)d_in[1];
    ushort* z = (ushort*)d_ws;                                  // 8192*128 bf16 = 2 MB
    float* denom = (float*)((char*)d_ws + (size_t)NROW * D_DIM * sizeof(ushort));
    float* pos_acc = denom + NROW;
    float* out = (float*)d_out;

    hipLaunchKernelGGL(k_normalize, dim3(NROW / 4), dim3(256), 0, stream,
                       xi, xj, z, denom, pos_acc);
    hipLaunchKernelGGL(k_gemm, dim3(64, 128), dim3(256), 0, stream,
                       z, denom, pos_acc);
    hipLaunchKernelGGL(k_final, dim3(1), dim3(256), 0, stream,
                       denom, pos_acc, out);
}

// Round 2
// 117.237 us; speedup vs baseline: 1.0815x; 1.0815x over previous
//
#include <hip/hip_runtime.h>
#include <stdint.h>

#define B_ROWS 4096
#define D_DIM 128
#define NROW 8192          // 2B
#define TEMP_INV 10.0f     // 1/0.1
#define L2EPS 1e-12f
#define LOG2E_X10 14.426950408889634f   // 10 / ln(2)

typedef __attribute__((ext_vector_type(8))) short short8;
typedef __attribute__((ext_vector_type(4))) float f32x4;

#define AS1 __attribute__((address_space(1)))
#define AS3 __attribute__((address_space(3)))

static __device__ inline void gload_lds16(const void* g, void* l) {
    __builtin_amdgcn_global_load_lds((const AS1 uint32_t*)g, (AS3 uint32_t*)l, 16, 0, 0);
}

static __device__ inline ushort f2bf(float f) {
    union { float f; uint32_t u; } v; v.f = f;
    uint32_t u = v.u;
    uint32_t r = (u + 0x7fffu + ((u >> 16) & 1u)) >> 16;   // RNE
    return (ushort)r;
}

// Kernel 1: L2-normalize rows of [x_i; x_j] -> bf16 Z; zero accumulators.
__global__ __launch_bounds__(256) void k_normalize(
        const float* __restrict__ xi, const float* __restrict__ xj,
        ushort* __restrict__ z, float* __restrict__ denom,
        float* __restrict__ pos_acc) {
    const int wave = threadIdx.x >> 6;
    const int lane = threadIdx.x & 63;
    const int row = blockIdx.x * 4 + wave;
    const float* src = (row < B_ROWS) ? (xi + (size_t)row * D_DIM)
                                      : (xj + (size_t)(row - B_ROWS) * D_DIM);
    float2 v = *(const float2*)(src + lane * 2);
    float ss = v.x * v.x + v.y * v.y;
#pragma unroll
    for (int m = 32; m >= 1; m >>= 1) ss += __shfl_xor(ss, m, 64);
    const float scale = 1.0f / fmaxf(sqrtf(ss), L2EPS);
    ushort2 o;
    o.x = f2bf(v.x * scale);
    o.y = f2bf(v.y * scale);
    *(ushort2*)(z + (size_t)row * D_DIM + lane * 2) = o;

    if (threadIdx.x < 4) denom[blockIdx.x * 4 + threadIdx.x] = 0.0f;
    if (blockIdx.x == 0 && threadIdx.x == 4) pos_acc[0] = 0.0f;
}

// Kernel 2: upper-triangle tiles of sim = Z Z^T (128x128 per block), fused
// exp row-sums AND col-sums (symmetry), positives on the ct==rt+32 band.
// LDS: XOR-swizzled (chunk k of row r at k^(r&15)), staged via global_load_lds.
__global__ __launch_bounds__(256) void k_gemm(
        const ushort* __restrict__ z, float* __restrict__ denom,
        float* __restrict__ pos_acc) {
    const int ct = blockIdx.x;          // col tile (128 wide)
    const int rt = blockIdx.y;          // row tile
    if (ct < rt) return;                // symmetry: upper triangle only

    __shared__ __align__(16) ushort lds_a[128 * 128];   // 32 KB
    __shared__ __align__(16) ushort lds_b[128 * 128];   // 32 KB
    const int t = threadIdx.x;
    const int rowbase = rt * 128, colbase = ct * 128;

    // Stage both tiles (each = 128 contiguous rows of Z = contiguous 32 KB).
    // LDS slot s holds global chunk (s>>4)*16 + ((s&15) ^ ((s>>4)&15)).
    const ushort* za = z + (size_t)rowbase * D_DIM;
    const ushort* zb = z + (size_t)colbase * D_DIM;
#pragma unroll
    for (int i = 0; i < 8; i++) {
        const int s = i * 256 + t;
        const int r = s >> 4;
        const int gchunk = (r << 4) | ((s & 15) ^ (r & 15));
        gload_lds16(za + gchunk * 8, &lds_a[s * 8]);
        gload_lds16(zb + gchunk * 8, &lds_b[s * 8]);
    }
    __syncthreads();

    const int wave = t >> 6, lane = t & 63;
    const int quad = lane >> 4, lc = lane & 15;
    const int wr = (wave & 1) * 64;     // wave quadrant: rows
    const int wc = (wave >> 1) * 64;    // wave quadrant: cols

    f32x4 acc[4][4];
#pragma unroll
    for (int i = 0; i < 4; i++)
#pragma unroll
        for (int j = 0; j < 4; j++) acc[i][j] = (f32x4){0.f, 0.f, 0.f, 0.f};

#pragma unroll
    for (int kk = 0; kk < 4; kk++) {
        const int chunk = ((kk * 4 + quad) ^ lc) * 8;   // swizzled, ushorts
        short8 a[4], b[4];
#pragma unroll
        for (int i = 0; i < 4; i++)
            a[i] = *(const short8*)&lds_a[(wr + i * 16 + lc) * D_DIM + chunk];
#pragma unroll
        for (int j = 0; j < 4; j++)
            b[j] = *(const short8*)&lds_b[(wc + j * 16 + lc) * D_DIM + chunk];
#pragma unroll
        for (int i = 0; i < 4; i++)
#pragma unroll
            for (int j = 0; j < 4; j++)
                acc[i][j] = __builtin_amdgcn_mfma_f32_16x16x32_bf16(a[i], b[j], acc[i][j], 0, 0, 0);
    }

    // Epilogue: e = exp(sim/T); add to row partial (this tile's rows) and,
    // for off-diagonal tiles, col partial (symmetric counterpart's rows).
    const bool diagblk = (rt == ct);
    const bool wavediag = (wr == wc);
    const bool posblk = (ct == rt + 32) && wavediag;  // col == row + 4096 band
    float rs[4][4];
#pragma unroll
    for (int i = 0; i < 4; i++)
#pragma unroll
        for (int r = 0; r < 4; r++) rs[i][r] = 0.f;
    float cs[4] = {0.f, 0.f, 0.f, 0.f};
    float posp = 0.f;

#pragma unroll
    for (int i = 0; i < 4; i++) {
#pragma unroll
        for (int j = 0; j < 4; j++) {
#pragma unroll
            for (int r = 0; r < 4; r++) {
                const float s = acc[i][j][r];
                float e = exp2f(s * LOG2E_X10);
                const bool ondiag = (i == j) && (lc == quad * 4 + r);
                if (diagblk && wavediag && ondiag) e = 0.f;  // exclude r==c
                rs[i][r] += e;
                cs[j] += e;
                if (posblk && ondiag) posp += s;
            }
        }
    }

    // Row sums: reduce over lc (lane bits 0-3) -> denom[tile rows].
#pragma unroll
    for (int i = 0; i < 4; i++)
#pragma unroll
        for (int r = 0; r < 4; r++) {
            float v = rs[i][r];
            v += __shfl_xor(v, 1, 64);
            v += __shfl_xor(v, 2, 64);
            v += __shfl_xor(v, 4, 64);
            v += __shfl_xor(v, 8, 64);
            if (lc == 0)
                atomicAdd(&denom[rowbase + wr + i * 16 + quad * 4 + r], v);
        }

    // Col sums: reduce over quad (lane bits 4-5) -> denom[tile cols].
    if (!diagblk) {
#pragma unroll
        for (int j = 0; j < 4; j++) {
            float v = cs[j];
            v += __shfl_xor(v, 16, 64);
            v += __shfl_xor(v, 32, 64);
            if (quad == 0)
                atomicAdd(&denom[colbase + wc + j * 16 + lc], v);
        }
    }

    if (posblk) {
#pragma unroll
        for (int m = 32; m >= 1; m >>= 1) posp += __shfl_xor(posp, m, 64);
        if (lane == 0) atomicAdd(pos_acc, posp);
    }
}

// Kernel 3: loss = (sum_r log(denom[r]) - 2*pos_sum/T) / (2B)
__global__ __launch_bounds__(1024) void k_final(
        const float* __restrict__ denom, const float* __restrict__ pos_acc,
        float* __restrict__ out) {
    __shared__ float red[16];
    const int t = threadIdx.x;
    float s = 0.f;
    for (int r = t; r < NROW; r += 1024) s += __logf(denom[r]);
#pragma unroll
    for (int m = 32; m >= 1; m >>= 1) s += __shfl_xor(s, m, 64);
    if ((t & 63) == 0) red[t >> 6] = s;
    __syncthreads();
    if (t == 0) {
        float total = 0.f;
#pragma unroll
        for (int i = 0; i < 16; i++) total += red[i];
        out[0] = (total - pos_acc[0] * 2.0f * TEMP_INV) / (float)NROW;
    }
}

extern "C" void kernel_launch(void* const* d_in, const int* in_sizes, int n_in,
                              void* d_out, int out_size, void* d_ws, size_t ws_size,
                              hipStream_t stream) {
    const float* xi = (const float*)d_in[0];
    const float* xj = (const float*)d_in[1];
    ushort* z = (ushort*)d_ws;                                  // 2 MB bf16
    float* denom = (float*)((char*)d_ws + (size_t)NROW * D_DIM * sizeof(ushort));
    float* pos_acc = denom + NROW;
    float* out = (float*)d_out;

    hipLaunchKernelGGL(k_normalize, dim3(NROW / 4), dim3(256), 0, stream,
                       xi, xj, z, denom, pos_acc);
    hipLaunchKernelGGL(k_gemm, dim3(64, 64), dim3(256), 0, stream,
                       z, denom, pos_acc);
    hipLaunchKernelGGL(k_final, dim3(1), dim3(1024), 0, stream,
                       denom, pos_acc, out);
}

// Round 4
// 97.557 us; speedup vs baseline: 1.2996x; 1.2017x over previous
//
#include <hip/hip_runtime.h>
#include <stdint.h>

#define D_DIM 128
#define NROW 8192          // 2B
#define TEMP_INV 10.0f     // 1/0.1
#define L2EPS 1e-12f
#define LOG2E_X10 14.426950408889634f   // 10 / ln(2)

typedef __attribute__((ext_vector_type(8))) short short8;
typedef __attribute__((ext_vector_type(4))) float f32x4;

#define AS1 __attribute__((address_space(1)))
#define AS3 __attribute__((address_space(3)))

static __device__ inline void gload_lds16(const void* g, void* l) {
    __builtin_amdgcn_global_load_lds((const AS1 uint32_t*)g, (AS3 uint32_t*)l, 16, 0, 0);
}

static __device__ inline ushort f2bf(float f) {
    union { float f; uint32_t u; } v; v.f = f;
    uint32_t u = v.u;
    uint32_t r = (u + 0x7fffu + ((u >> 16) & 1u)) >> 16;   // RNE
    return (ushort)r;
}

// K1: L2-normalize rows of [x_i; x_j] -> bf16 Z; zero scalar accumulators.
__global__ __launch_bounds__(256) void k_normalize(
        const float* __restrict__ xi, const float* __restrict__ xj,
        ushort* __restrict__ z, float* __restrict__ pos_acc,
        float* __restrict__ logsum) {
    const int wave = threadIdx.x >> 6;
    const int lane = threadIdx.x & 63;
    const int row = blockIdx.x * 4 + wave;
    const float* src = (row < 4096) ? (xi + (size_t)row * D_DIM)
                                    : (xj + (size_t)(row - 4096) * D_DIM);
    float2 v = *(const float2*)(src + lane * 2);
    float ss = v.x * v.x + v.y * v.y;
#pragma unroll
    for (int m = 32; m >= 1; m >>= 1) ss += __shfl_xor(ss, m, 64);
    const float scale = 1.0f / fmaxf(sqrtf(ss), L2EPS);
    ushort2 o;
    o.x = f2bf(v.x * scale);
    o.y = f2bf(v.y * scale);
    *(ushort2*)(z + (size_t)row * D_DIM + lane * 2) = o;

    if (blockIdx.x == 0 && threadIdx.x == 0) { pos_acc[0] = 0.0f; logsum[0] = 0.0f; }
}

// K2: block (rb=bid>>3, cc=bid&7) computes sim rows [rb*128,+128) x cols
// [cc*1024,+1024): A-band staged once (XOR-swizzled LDS), A-frags hoisted to
// registers; B streamed as 16 double-buffered 64x128 tiles via global_load_lds.
// Fused exp row-sums -> denom_part[cc][row] (single writer, no atomics);
// positives on the cg == rg^4096 band.
__global__ __launch_bounds__(256, 2) void k_gemm(
        const ushort* __restrict__ z, float* __restrict__ denom_part,
        float* __restrict__ pos_acc) {
    __shared__ __align__(16) ushort lds_a[128 * 128];     // 32 KB
    __shared__ __align__(16) ushort lds_b[2][64 * 128];   // 2 x 16 KB

    const int bid = blockIdx.x;
    const int t = threadIdx.x;
    const int wave = t >> 6, lane = t & 63;
    const int quad = lane >> 4, lc = lane & 15;

    const int rb = bid >> 3;            // row band 0..63
    const int cc = bid & 7;             // col chunk 0..7
    const int rowbase = rb * 128;
    const int colbase = cc * 1024;

    // Stage A band (contiguous 32 KB of Z) + first B tile; XOR swizzle:
    // 16B chunk g of row r lands at slot g ^ (r&15).
    {
        const ushort* za = z + (size_t)rowbase * D_DIM;
#pragma unroll
        for (int q = 0; q < 8; q++) {
            const int s = q * 256 + t;
            const int r = s >> 4;
            const int gc = (s & 15) ^ (r & 15);
            gload_lds16(za + (size_t)r * D_DIM + gc * 8, &lds_a[s * 8]);
        }
        const ushort* zb = z + (size_t)colbase * D_DIM;
#pragma unroll
        for (int q = 0; q < 4; q++) {
            const int s = q * 256 + t;
            const int r = s >> 4;
            const int gc = (s & 15) ^ (r & 15);
            gload_lds16(zb + (size_t)r * D_DIM + gc * 8, &lds_b[0][s * 8]);
        }
        asm volatile("s_waitcnt vmcnt(0)" ::: "memory");
        __syncthreads();
    }

    // Hoist A fragments: wave owns rows [wave*32, +32): 2 row-tiles x 4 K-chunks.
    short8 afr[2][4];
#pragma unroll
    for (int i = 0; i < 2; i++)
#pragma unroll
        for (int k = 0; k < 4; k++)
            afr[i][k] = *(const short8*)
                &lds_a[(wave * 32 + i * 16 + lc) * D_DIM + ((k * 4 + quad) ^ lc) * 8];

    const bool diagblk = (cc == (rb >> 3));
    const bool posblk  = (cc == ((rb ^ 32) >> 3));
    const int diag_it2 = rb & 7;
    const int pos_it2  = (rb ^ 32) & 7;

    float rs[2][4] = {{0.f,0.f,0.f,0.f},{0.f,0.f,0.f,0.f}};
    float posp = 0.f;
    const int rgbase = rowbase + wave * 32 + quad * 4;   // + i*16 + r

    for (int it = 0; it < 16; it++) {
        const int cur = it & 1;
        if (it < 15) {  // prefetch next B tile into the other buffer
            const ushort* zb = z + (size_t)(colbase + (it + 1) * 64) * D_DIM;
#pragma unroll
            for (int q = 0; q < 4; q++) {
                const int s = q * 256 + t;
                const int r = s >> 4;
                const int gc = (s & 15) ^ (r & 15);
                gload_lds16(zb + (size_t)r * D_DIM + gc * 8, &lds_b[cur ^ 1][s * 8]);
            }
        }

        f32x4 acc[2][4];
#pragma unroll
        for (int i = 0; i < 2; i++)
#pragma unroll
            for (int j = 0; j < 4; j++) acc[i][j] = (f32x4){0.f, 0.f, 0.f, 0.f};

#pragma unroll
        for (int j = 0; j < 4; j++) {
            short8 bfr[4];
#pragma unroll
            for (int k = 0; k < 4; k++)
                bfr[k] = *(const short8*)
                    &lds_b[cur][(j * 16 + lc) * D_DIM + ((k * 4 + quad) ^ lc) * 8];
#pragma unroll
            for (int k = 0; k < 4; k++) {
                acc[0][j] = __builtin_amdgcn_mfma_f32_16x16x32_bf16(afr[0][k], bfr[k], acc[0][j], 0, 0, 0);
                acc[1][j] = __builtin_amdgcn_mfma_f32_16x16x32_bf16(afr[1][k], bfr[k], acc[1][j], 0, 0, 0);
            }
        }

        const bool dit = diagblk && ((it >> 1) == diag_it2);
        const bool pit = posblk && ((it >> 1) == pos_it2);
        if (dit || pit) {   // careful path: <= 2 of 16 iters, <= 1/8 of blocks
#pragma unroll
            for (int i = 0; i < 2; i++)
#pragma unroll
                for (int j = 0; j < 4; j++)
#pragma unroll
                    for (int r = 0; r < 4; r++) {
                        const float s = acc[i][j][r];
                        float e = exp2f(s * LOG2E_X10);
                        const int rg = rgbase + i * 16 + r;
                        const int cg = colbase + it * 64 + j * 16 + lc;
                        if (dit && rg == cg) e = 0.f;            // exclude diag
                        if (pit && cg == (rg ^ 4096)) posp += s; // positive
                        rs[i][r] += e;
                    }
        } else {            // hot path
#pragma unroll
            for (int i = 0; i < 2; i++)
#pragma unroll
                for (int j = 0; j < 4; j++)
#pragma unroll
                    for (int r = 0; r < 4; r++)
                        rs[i][r] += exp2f(acc[i][j][r] * LOG2E_X10);
        }

        asm volatile("s_waitcnt vmcnt(0)" ::: "memory");
        __syncthreads();
    }

    // Row partials: reduce over the 16 col-lanes, one store per row.
#pragma unroll
    for (int i = 0; i < 2; i++)
#pragma unroll
        for (int r = 0; r < 4; r++) {
            float v = rs[i][r];
            v += __shfl_xor(v, 1, 64);
            v += __shfl_xor(v, 2, 64);
            v += __shfl_xor(v, 4, 64);
            v += __shfl_xor(v, 8, 64);
            if (lc == 0)
                denom_part[(size_t)cc * NROW + rgbase + i * 16 + r] = v;
        }

    if (posblk) {
#pragma unroll
        for (int m = 32; m >= 1; m >>= 1) posp += __shfl_xor(posp, m, 64);
        if (lane == 0) atomicAdd(pos_acc, posp);
    }
}

// K3: one row per thread: denom = sum of 8 partials; log; wave-reduce; atomic.
__global__ __launch_bounds__(256) void k_logsum(
        const float* __restrict__ denom_part, float* __restrict__ logsum) {
    const int row = blockIdx.x * 256 + threadIdx.x;
    float d = 0.f;
#pragma unroll
    for (int p = 0; p < 8; p++) d += denom_part[(size_t)p * NROW + row];
    float v = __logf(d);
#pragma unroll
    for (int m = 32; m >= 1; m >>= 1) v += __shfl_xor(v, m, 64);
    if ((threadIdx.x & 63) == 0) atomicAdd(logsum, v);
}

// K4: combine.
__global__ void k_combine(const float* __restrict__ logsum,
                          const float* __restrict__ pos_acc,
                          float* __restrict__ out) {
    out[0] = (logsum[0] - pos_acc[0] * TEMP_INV) / (float)NROW;
}

extern "C" void kernel_launch(void* const* d_in, const int* in_sizes, int n_in,
                              void* d_out, int out_size, void* d_ws, size_t ws_size,
                              hipStream_t stream) {
    const float* xi = (const float*)d_in[0];
    const float* xj = (const float*)d_in[1];
    ushort* z = (ushort*)d_ws;                                   // 2 MB bf16
    float* denom_part = (float*)((char*)d_ws + (size_t)NROW * D_DIM * sizeof(ushort)); // 8 x 8192 f32
    float* pos_acc = denom_part + 8 * NROW;
    float* logsum = pos_acc + 1;
    float* out = (float*)d_out;

    hipLaunchKernelGGL(k_normalize, dim3(NROW / 4), dim3(256), 0, stream,
                       xi, xj, z, pos_acc, logsum);
    hipLaunchKernelGGL(k_gemm, dim3(512), dim3(256), 0, stream,
                       z, denom_part, pos_acc);
    hipLaunchKernelGGL(k_logsum, dim3(NROW / 256), dim3(256), 0, stream,
                       denom_part, logsum);
    hipLaunchKernelGGL(k_combine, dim3(1), dim3(1), 0, stream,
                       logsum, pos_acc, out);
}